// Round 3
// baseline (1099.275 us; speedup 1.0000x reference)
//
#include <hip/hip_runtime.h>
#include <hip/hip_bf16.h>

#define LN_EPS 1e-5f

typedef __attribute__((ext_vector_type(8))) short bf16x8;    // 8 bf16 = 4 VGPRs
typedef __attribute__((ext_vector_type(16))) float f32x16;   // 32x32 MFMA acc

__device__ __forceinline__ unsigned short f2bf(float f) {
    unsigned int u = __float_as_uint(f);
    u += 0x7fffu + ((u >> 16) & 1u);   // RNE (used only in pack kernels)
    return (unsigned short)(u >> 16);
}
__device__ __forceinline__ float bf2f(unsigned short s) {
    return __uint_as_float(((unsigned int)s) << 16);
}
// fast pack: two floats -> two bf16 (round-half-up) in one dword via v_perm
__device__ __forceinline__ unsigned int pack_bf2(float a, float b) {
    unsigned int ua = __float_as_uint(a) + 0x8000u;
    unsigned int ub = __float_as_uint(b) + 0x8000u;
    return __builtin_amdgcn_perm(ub, ua, 0x07060302);  // {ub.hi16, ua.hi16}
}

// N=65536, D=256, Hd=1024, E=8
#define DD   256
#define HD   1024
#define NE   8
#define TN   64

// XOR swizzle: 16B granules, granule ^= (row & 7). Row stride 256 shorts (no pad).
// Makes every b128 read / b64 write in this kernel exactly minimum-cycle (bank-uniform).
__device__ __forceinline__ int swz(int row, int col) {
    return row * 256 + (((col >> 3) ^ (row & 7)) << 3) + (col & 7);
}

// ---------------- weight packing (fragment-major bf16), unchanged ----------------
// pw1[e][g][n][j] = bf16(W1[e][g*8+j][n]),  g<32, n<1024, j<8
__global__ void pack_w1(const float* __restrict__ W1, unsigned short* __restrict__ pw1) {
    int t = blockIdx.x * 256 + threadIdx.x;
    int n = t & 1023, g = (t >> 10) & 31, e = t >> 15;
    const float* src = W1 + ((size_t)(e * 256 + g * 8)) * 1024 + n;
    union { unsigned short s[8]; int4 v; } u;
#pragma unroll
    for (int j = 0; j < 8; ++j) u.s[j] = f2bf(src[(size_t)j * 1024]);
    *(int4*)(pw1 + (size_t)t * 8) = u.v;
}
// pw2[e][g][n][j] = bf16(W2[e][g*8+j][n]),  g<128, n<256, j<8
__global__ void pack_w2(const float* __restrict__ W2, unsigned short* __restrict__ pw2) {
    int t = blockIdx.x * 256 + threadIdx.x;
    int n = t & 255, g = (t >> 8) & 127, e = t >> 15;
    const float* src = W2 + ((size_t)(e * 1024 + g * 8)) * 256 + n;
    union { unsigned short s[8]; int4 v; } u;
#pragma unroll
    for (int j = 0; j < 8; ++j) u.s[j] = f2bf(src[(size_t)j * 256]);
    *(int4*)(pw2 + (size_t)t * 8) = u.v;
}

#define MFMA32(a, b, c) __builtin_amdgcn_mfma_f32_32x32x16_bf16(a, b, c, 0, 0, 0)

// ---------------- fused MoE block ----------------
__global__ __launch_bounds__(256, 2)
void moe_main(const float* __restrict__ H, const float* __restrict__ gate_w,
              const float* __restrict__ gate_b, const float* __restrict__ b1,
              const float* __restrict__ b2, const float* __restrict__ ln_g,
              const float* __restrict__ ln_b,
              const unsigned short* __restrict__ pw1,
              const unsigned short* __restrict__ pw2,
              float* __restrict__ out)
{
    __shared__ unsigned short sH[TN * 256];     // 32768 B, swizzled
    __shared__ unsigned short sHC[TN * 256];    // 32768 B, swizzled
    __shared__ float sWts[TN * NE];             // 2048 B
    __shared__ float sRedS[TN * 4];             // 1024 B
    __shared__ float sRedQ[TN * 4];             // 1024 B
    __shared__ float sMu[TN * 2];               // 512 B   -> total ~70 KB, 2 blocks/CU

    const int tid  = threadIdx.x;
    const int lane = tid & 63;
    const int wave = tid >> 6;
    const int l31  = lane & 31;
    const int h32  = lane >> 5;
    const int node0 = blockIdx.x * TN;
    const int ncol  = wave * 64;     // wave's 64-col slice (hd within chunk; d for output)

    // ---- stage H tile (fp32 -> bf16, swizzled) ----
    for (int i = tid; i < TN * 64; i += 256) {
        int row = i >> 6, c4 = i & 63;
        const float4 v = ((const float4*)(H + (size_t)(node0 + row) * DD))[c4];
        unsigned int lo = pack_bf2(v.x, v.y);
        unsigned int hi = pack_bf2(v.z, v.w);
        *(uint2*)&sH[swz(row, c4 * 4)] = make_uint2(lo, hi);
    }

    // ---- prime weight queue (s=0, stage1 ks=0..3) before barriers ----
    bf16x8 q[4][2];
    {
        const unsigned short* w1b = pw1 + (((size_t)h32) * 1024 + ncol + l31) * 8; // e=0,c=0
#pragma unroll
        for (int ks = 0; ks < 4; ++ks) {
            q[ks][0] = *(const bf16x8*)(w1b + ((size_t)ks * 2 * 1024) * 8);
            q[ks][1] = *(const bf16x8*)(w1b + ((size_t)ks * 2 * 1024 + 32) * 8);
        }
    }
    __syncthreads();

    // ---- gating logits (from swizzled sH; gate_w straight from global/L2) ----
    for (int p = tid; p < TN * NE; p += 256) {
        int n = p >> 3, e = p & 7;
        float acc = gate_b[e];
        for (int g = 0; g < 32; ++g) {
            const unsigned short* rowp = &sH[n * 256 + (((g ^ (n & 7)) << 3))];
            const float* gwp = &gate_w[g * 64 + e];
#pragma unroll
            for (int j = 0; j < 8; ++j)
                acc += bf2f(rowp[j]) * gwp[j * 8];
        }
        sWts[p] = acc;
    }
    __syncthreads();
    if (tid < TN) {
        float lg[8], mx = -1e30f;
#pragma unroll
        for (int e = 0; e < 8; ++e) { lg[e] = sWts[tid * 8 + e]; mx = fmaxf(mx, lg[e]); }
        float s = 0.f;
#pragma unroll
        for (int e = 0; e < 8; ++e) { lg[e] = __expf(lg[e] - mx); s += lg[e]; }
        float inv = 1.0f / s;
#pragma unroll
        for (int e = 0; e < 8; ++e) sWts[tid * 8 + e] = lg[e] * inv;
    }
    __syncthreads();

    // ---- oacc C-init: residual H + sum_e w_e * b2[e]  (folded epilogue) ----
    f32x16 oacc[2][2];   // [im: d 32-tile][in: node 32-tile]; col=node=l31, row=d local
    {
        float wv[2][8];
#pragma unroll
        for (int in = 0; in < 2; ++in)
#pragma unroll
            for (int e2 = 0; e2 < 8; ++e2) wv[in][e2] = sWts[(in * 32 + l31) * 8 + e2];
#pragma unroll
        for (int im = 0; im < 2; ++im)
#pragma unroll
            for (int rq = 0; rq < 4; ++rq) {
                const int db = ncol + im * 32 + rq * 8 + h32 * 4;
                float4 bacc[2];
#pragma unroll
                for (int in = 0; in < 2; ++in)
                    bacc[in] = *(const float4*)&H[(size_t)(node0 + in * 32 + l31) * DD + db];
#pragma unroll
                for (int e2 = 0; e2 < 8; ++e2) {
                    const float4 bv = *(const float4*)&b2[e2 * DD + db];
#pragma unroll
                    for (int in = 0; in < 2; ++in) {
                        bacc[in].x += wv[in][e2] * bv.x;
                        bacc[in].y += wv[in][e2] * bv.y;
                        bacc[in].z += wv[in][e2] * bv.z;
                        bacc[in].w += wv[in][e2] * bv.w;
                    }
                }
#pragma unroll
                for (int in = 0; in < 2; ++in) {
                    oacc[im][in][rq * 4 + 0] = bacc[in].x;
                    oacc[im][in][rq * 4 + 1] = bacc[in].y;
                    oacc[im][in][rq * 4 + 2] = bacc[in].z;
                    oacc[im][in][rq * 4 + 3] = bacc[in].w;
                }
            }
    }

    // ---- main loop: 32 (e,c) iterations ----
#pragma unroll 1
    for (int s = 0; s < 32; ++s) {
        const int e = s >> 2, c = s & 3;
        const int sn = (s + 1) & 31;
        const int en = sn >> 2, cn = sn & 3;

        const unsigned short* w1b = pw1 +
            (((size_t)e * 32 + h32) * 1024 + c * 256 + ncol + l31) * 8;
        const unsigned short* w2b = pw2 +
            (((size_t)e * 128 + c * 32 + h32) * 256 + ncol + l31) * 8;
        const unsigned short* w1n = pw1 +
            (((size_t)en * 32 + h32) * 1024 + cn * 256 + ncol + l31) * 8;

        float wge[2];
#pragma unroll
        for (int in = 0; in < 2; ++in) wge[in] = sWts[(in * 32 + l31) * 8 + e];

        // ---- stage 1: acc1[hd][node], C-init = b1 bias ----
        f32x16 acc1[2][2];
#pragma unroll
        for (int im = 0; im < 2; ++im) {
            float4 bv[4];
#pragma unroll
            for (int rq = 0; rq < 4; ++rq)
                bv[rq] = *(const float4*)&b1[e * HD + c * 256 + ncol + im * 32 + rq * 8 + h32 * 4];
#pragma unroll
            for (int in = 0; in < 2; ++in)
#pragma unroll
                for (int rq = 0; rq < 4; ++rq) {
                    acc1[im][in][rq * 4 + 0] = bv[rq].x;
                    acc1[im][in][rq * 4 + 1] = bv[rq].y;
                    acc1[im][in][rq * 4 + 2] = bv[rq].z;
                    acc1[im][in][rq * 4 + 3] = bv[rq].w;
                }
        }

#pragma unroll
        for (int ks = 0; ks < 16; ++ks) {
            const int slot = ks & 3;
            bf16x8 act0 = *(const bf16x8*)&sH[swz(l31,      ks * 16 + h32 * 8)];
            bf16x8 act1 = *(const bf16x8*)&sH[swz(32 + l31, ks * 16 + h32 * 8)];
            bf16x8 n0, n1;
            if (ks < 12) {
                n0 = *(const bf16x8*)(w1b + ((size_t)(ks + 4) * 2 * 1024) * 8);
                n1 = *(const bf16x8*)(w1b + ((size_t)(ks + 4) * 2 * 1024 + 32) * 8);
            } else {
                n0 = *(const bf16x8*)(w2b + ((size_t)(ks - 12) * 2 * 256) * 8);
                n1 = *(const bf16x8*)(w2b + ((size_t)(ks - 12) * 2 * 256 + 32) * 8);
            }
            acc1[0][0] = MFMA32(q[slot][0], act0, acc1[0][0]);
            acc1[0][1] = MFMA32(q[slot][0], act1, acc1[0][1]);
            acc1[1][0] = MFMA32(q[slot][1], act0, acc1[1][0]);
            acc1[1][1] = MFMA32(q[slot][1], act1, acc1[1][1]);
            q[slot][0] = n0; q[slot][1] = n1;
        }

        // ---- epilogue -> sHC: relu * gate, fast pack, b64 swizzled (bank-uniform) ----
#pragma unroll
        for (int im = 0; im < 2; ++im)
#pragma unroll
            for (int in = 0; in < 2; ++in) {
                const float w = wge[in];
                const int row = in * 32 + l31;
#pragma unroll
                for (int rq = 0; rq < 4; ++rq) {
                    float v0 = fmaxf(acc1[im][in][rq * 4 + 0], 0.f) * w;
                    float v1 = fmaxf(acc1[im][in][rq * 4 + 1], 0.f) * w;
                    float v2 = fmaxf(acc1[im][in][rq * 4 + 2], 0.f) * w;
                    float v3 = fmaxf(acc1[im][in][rq * 4 + 3], 0.f) * w;
                    *(uint2*)&sHC[swz(row, ncol + im * 32 + rq * 8 + h32 * 4)] =
                        make_uint2(pack_bf2(v0, v1), pack_bf2(v2, v3));
                }
            }
        __syncthreads();

        // ---- stage 2: oacc[d][node] += W2chunk^T @ hc^T ----
#pragma unroll
        for (int ks = 0; ks < 16; ++ks) {
            const int slot = ks & 3;
            bf16x8 act0 = *(const bf16x8*)&sHC[swz(l31,      ks * 16 + h32 * 8)];
            bf16x8 act1 = *(const bf16x8*)&sHC[swz(32 + l31, ks * 16 + h32 * 8)];
            bf16x8 n0, n1;
            if (ks < 12) {
                n0 = *(const bf16x8*)(w2b + ((size_t)(ks + 4) * 2 * 256) * 8);
                n1 = *(const bf16x8*)(w2b + ((size_t)(ks + 4) * 2 * 256 + 32) * 8);
            } else {
                n0 = *(const bf16x8*)(w1n + ((size_t)(ks - 12) * 2 * 1024) * 8);
                n1 = *(const bf16x8*)(w1n + ((size_t)(ks - 12) * 2 * 1024 + 32) * 8);
            }
            oacc[0][0] = MFMA32(q[slot][0], act0, oacc[0][0]);
            oacc[0][1] = MFMA32(q[slot][0], act1, oacc[0][1]);
            oacc[1][0] = MFMA32(q[slot][1], act0, oacc[1][0]);
            oacc[1][1] = MFMA32(q[slot][1], act1, oacc[1][1]);
            q[slot][0] = n0; q[slot][1] = n1;
        }
        __syncthreads();
    }

    // ---- LayerNorm (residual & bias already folded into oacc) ----
    float sum[2], sum2[2];
#pragma unroll
    for (int in = 0; in < 2; ++in) {
        float s = 0.f, s2 = 0.f;
#pragma unroll
        for (int im = 0; im < 2; ++im)
#pragma unroll
            for (int r = 0; r < 16; ++r) { float x = oacc[im][in][r]; s += x; s2 += x * x; }
        s  += __shfl_xor(s, 32);
        s2 += __shfl_xor(s2, 32);
        sum[in] = s; sum2[in] = s2;
    }
    if (h32 == 0) {
#pragma unroll
        for (int in = 0; in < 2; ++in) {
            sRedS[(in * 32 + l31) * 4 + wave] = sum[in];
            sRedQ[(in * 32 + l31) * 4 + wave] = sum2[in];
        }
    }
    __syncthreads();
    if (tid < TN) {
        float s = 0.f, s2 = 0.f;
#pragma unroll
        for (int w2 = 0; w2 < 4; ++w2) { s += sRedS[tid * 4 + w2]; s2 += sRedQ[tid * 4 + w2]; }
        float mu  = s * (1.0f / 256.0f);
        float var = s2 * (1.0f / 256.0f) - mu * mu;
        sMu[tid * 2] = mu;
        sMu[tid * 2 + 1] = rsqrtf(var + LN_EPS);
    }
    __syncthreads();

#pragma unroll
    for (int im = 0; im < 2; ++im)
#pragma unroll
        for (int rq = 0; rq < 4; ++rq) {
            const int db = ncol + im * 32 + rq * 8 + h32 * 4;
            const float4 lgv = *(const float4*)&ln_g[db];
            const float4 lbv = *(const float4*)&ln_b[db];
#pragma unroll
            for (int in = 0; in < 2; ++in) {
                const int node = in * 32 + l31;
                const float mu = sMu[node * 2], rs = sMu[node * 2 + 1];
                float4 y;
                y.x = (oacc[im][in][rq * 4 + 0] - mu) * rs * lgv.x + lbv.x;
                y.y = (oacc[im][in][rq * 4 + 1] - mu) * rs * lgv.y + lbv.y;
                y.z = (oacc[im][in][rq * 4 + 2] - mu) * rs * lgv.z + lbv.z;
                y.w = (oacc[im][in][rq * 4 + 3] - mu) * rs * lgv.w + lbv.w;
                *(float4*)&out[(size_t)(node0 + node) * DD + db] = y;
            }
        }
}

extern "C" void kernel_launch(void* const* d_in, const int* in_sizes, int n_in,
                              void* d_out, int out_size, void* d_ws, size_t ws_size,
                              hipStream_t stream) {
    const float* H   = (const float*)d_in[0];
    const float* gw  = (const float*)d_in[1];
    const float* gb  = (const float*)d_in[2];
    const float* W1  = (const float*)d_in[3];
    const float* b1  = (const float*)d_in[4];
    const float* W2  = (const float*)d_in[5];
    const float* b2  = (const float*)d_in[6];
    const float* lng = (const float*)d_in[7];
    const float* lnb = (const float*)d_in[8];
    float* out = (float*)d_out;

    unsigned short* pw1 = (unsigned short*)d_ws;                 // 4 MB
    unsigned short* pw2 = pw1 + (size_t)8 * 32 * 1024 * 8;       // 4 MB

    hipLaunchKernelGGL(pack_w1, dim3(1024), dim3(256), 0, stream, W1, pw1);
    hipLaunchKernelGGL(pack_w2, dim3(1024), dim3(256), 0, stream, W2, pw2);
    hipLaunchKernelGGL(moe_main, dim3(65536 / TN), dim3(256), 0, stream,
                       H, gw, gb, b1, b2, lng, lnb, pw1, pw2, out);
}